// Round 2
// baseline (1186.429 us; speedup 1.0000x reference)
//
#include <hip/hip_runtime.h>

// Seq2Seq LSTM (enc 512 + dec 256 steps), H=50, B=2048, in/out dim 1.
//
// Round-2 layout: 2 waves (128 thr) per batch element. Wave w owns hidden
// units [25w, 25w+25). Within a wave, lane pair (2m,2m+1) owns unit u=25w+m:
//   even lane: k = 0..23   (24 weights/gate, float4-aligned)
//   odd  lane: k = 24..49  (24 main + 2 tail weights/gate, float4-aligned)
// -> 104 weight VGPRs/lane (4 gates), fits the 128-VGPR budget of
// __launch_bounds__(128,4) => 4 waves/SIMD. Round-1's 200-reg/lane layout
// overflowed into AGPRs (VGPR_Count=128) and paid a v_accvgpr_read per FMA.
//
// Gate partial sums combine across the lane pair with one shfl_xor(1) (DPP).
// h is exchanged via a double-buffered LDS array -> 1 barrier per step.

#define HID 50
#define SEQ 512
#define TGT 256
#define UPW 25     // units per wave
#define KMAIN 24   // float4-aligned k-span per half; odd half adds tail k=48,49

__device__ __forceinline__ float sigm(float x) {
    return 1.0f / (1.0f + __expf(-x));            // +-inf safe
}
__device__ __forceinline__ float tanh_(float x) {
    return 2.0f / (1.0f + __expf(-2.0f * x)) - 1.0f;
}

// Load this lane's weight slice for one LSTM layer into registers.
#define LOAD_W(Wih, Whh, Bih, Bhh)                                    \
    {                                                                 \
        _Pragma("unroll")                                             \
        for (int g = 0; g < 4; ++g) {                                 \
            const float* row = (Whh) + (size_t)(g * HID + u) * HID;   \
            _Pragma("unroll")                                         \
            for (int k = 0; k < KMAIN; ++k) wk[g][k] = row[k0 + k];   \
            wt[g][0] = half ? row[48] : 0.0f;                         \
            wt[g][1] = half ? row[49] : 0.0f;                         \
            wx[g] = (Wih)[g * HID + u];                               \
            bb[g] = (Bih)[g * HID + u] + (Bhh)[g * HID + u];          \
        }                                                             \
    }

// One LSTM step: gates from broadcast h (LDS, this lane's k-slice) +
// reg-resident weights; pair-combine via shfl_xor(1); defines hn, updates c.
#define STEP_GATES(xv, hb)                                            \
    float a0 = 0.f, a1 = 0.f, a2 = 0.f, a3 = 0.f;                     \
    {                                                                 \
        const float4* h4 = (const float4*)((hb) + k0);                \
        _Pragma("unroll")                                             \
        for (int q = 0; q < 6; ++q) {                                 \
            float4 hv = h4[q];                                        \
            const int kb = 4 * q;                                     \
            a0 = fmaf(wk[0][kb + 0], hv.x, a0);                       \
            a1 = fmaf(wk[1][kb + 0], hv.x, a1);                       \
            a2 = fmaf(wk[2][kb + 0], hv.x, a2);                       \
            a3 = fmaf(wk[3][kb + 0], hv.x, a3);                       \
            a0 = fmaf(wk[0][kb + 1], hv.y, a0);                       \
            a1 = fmaf(wk[1][kb + 1], hv.y, a1);                       \
            a2 = fmaf(wk[2][kb + 1], hv.y, a2);                       \
            a3 = fmaf(wk[3][kb + 1], hv.y, a3);                       \
            a0 = fmaf(wk[0][kb + 2], hv.z, a0);                       \
            a1 = fmaf(wk[1][kb + 2], hv.z, a1);                       \
            a2 = fmaf(wk[2][kb + 2], hv.z, a2);                       \
            a3 = fmaf(wk[3][kb + 2], hv.z, a3);                       \
            a0 = fmaf(wk[0][kb + 3], hv.w, a0);                       \
            a1 = fmaf(wk[1][kb + 3], hv.w, a1);                       \
            a2 = fmaf(wk[2][kb + 3], hv.w, a2);                       \
            a3 = fmaf(wk[3][kb + 3], hv.w, a3);                       \
        }                                                             \
        float h48 = (hb)[48], h49 = (hb)[49];                         \
        a0 = fmaf(wt[0][0], h48, a0); a0 = fmaf(wt[0][1], h49, a0);   \
        a1 = fmaf(wt[1][0], h48, a1); a1 = fmaf(wt[1][1], h49, a1);   \
        a2 = fmaf(wt[2][0], h48, a2); a2 = fmaf(wt[2][1], h49, a2);   \
        a3 = fmaf(wt[3][0], h48, a3); a3 = fmaf(wt[3][1], h49, a3);   \
    }                                                                 \
    a0 += __shfl_xor(a0, 1, 64);                                      \
    a1 += __shfl_xor(a1, 1, 64);                                      \
    a2 += __shfl_xor(a2, 1, 64);                                      \
    a3 += __shfl_xor(a3, 1, 64);                                      \
    a0 = fmaf(wx[0], (xv), a0 + bb[0]);                               \
    a1 = fmaf(wx[1], (xv), a1 + bb[1]);                               \
    a2 = fmaf(wx[2], (xv), a2 + bb[2]);                               \
    a3 = fmaf(wx[3], (xv), a3 + bb[3]);                               \
    float gi = sigm(a0);                                              \
    float gf = sigm(a1);                                              \
    float gg = tanh_(a2);                                             \
    float go = sigm(a3);                                              \
    c = fmaf(gf, c, gi * gg);                                         \
    float hn = go * tanh_(c);

extern "C" __global__ void __launch_bounds__(128, 4)
seq2seq_kernel(const float* __restrict__ src,
               const float* __restrict__ eWih, const float* __restrict__ eWhh,
               const float* __restrict__ eBih, const float* __restrict__ eBhh,
               const float* __restrict__ dWih, const float* __restrict__ dWhh,
               const float* __restrict__ dBih, const float* __restrict__ dBhh,
               const float* __restrict__ fcW, const float* __restrict__ fcB,
               float* __restrict__ out) {
    const int b    = blockIdx.x;
    const int tid  = threadIdx.x;        // 0..127
    const int w    = tid >> 6;           // wave 0/1
    const int j    = tid & 63;           // lane
    const int half = j & 1;              // k-half: 0 -> k<24, 1 -> k>=24
    const int ju   = j >> 1;             // pair index 0..31
    const bool act = (ju < UPW);         // lanes 50..63 of each wave idle
    const int u    = w * UPW + (act ? ju : (UPW - 1));  // clamped unit id
    const int k0   = half * KMAIN;       // 0 or 24 (both float4-aligned)

    __shared__ float hbuf[2][64];        // double-buffered h state
    __shared__ float pbuf[2][2];         // decoder fc partials per wave
    if (tid < 64) { hbuf[0][tid] = 0.0f; hbuf[1][tid] = 0.0f; }
    __syncthreads();

    float wk[4][KMAIN];                  // main weights (96 regs)
    float wt[4][2];                      // tail k=48,49 (odd half only)
    float wx[4], bb[4];
    float c = 0.0f;
    int cur = 0;

    // ---------------- encoder: 512 steps ----------------
    LOAD_W(eWih, eWhh, eBih, eBhh);
    const float* sb = src + (size_t)b * SEQ;
    float x = sb[0];
    for (int t = 0; t < SEQ; ++t) {
        float xn = sb[(t + 1 < SEQ) ? (t + 1) : 0];   // prefetch next x
        STEP_GATES(x, hbuf[cur])
        if (act && half == 0) hbuf[cur ^ 1][u] = hn;  // write into other buffer
        __syncthreads();                              // single barrier per step
        cur ^= 1;
        x = xn;
    }

    // ---------------- decoder: 256 steps ----------------
    LOAD_W(dWih, dWhh, dBih, dBhh);
    const float fw = (act && half == 0) ? fcW[u] : 0.0f;
    const float fb = fcB[0];
    float* ob = out + (size_t)b * TGT;

    x = 0.0f;                                         // decoder_input = zeros
    for (int t = 0; t < TGT; ++t) {
        STEP_GATES(x, hbuf[cur])
        // fc partial: even-active lanes contribute fcW[u]*h[u]
        float p = fw * hn;
#pragma unroll
        for (int off = 32; off > 0; off >>= 1) p += __shfl_xor(p, off, 64);
        if (j == 0) pbuf[cur][w] = p;
        if (act && half == 0) hbuf[cur ^ 1][u] = hn;
        __syncthreads();
        float y = pbuf[cur][0] + pbuf[cur][1] + fb;   // all lanes compute y
        if (tid == 0) ob[t] = y;
        cur ^= 1;
        x = y;                                        // feed back as next input
    }
}

extern "C" void kernel_launch(void* const* d_in, const int* in_sizes, int n_in,
                              void* d_out, int out_size, void* d_ws, size_t ws_size,
                              hipStream_t stream) {
    const float* src  = (const float*)d_in[0];
    const float* eWih = (const float*)d_in[1];
    const float* eWhh = (const float*)d_in[2];
    const float* eBih = (const float*)d_in[3];
    const float* eBhh = (const float*)d_in[4];
    const float* dWih = (const float*)d_in[5];
    const float* dWhh = (const float*)d_in[6];
    const float* dBih = (const float*)d_in[7];
    const float* dBhh = (const float*)d_in[8];
    const float* fcW  = (const float*)d_in[9];
    const float* fcB  = (const float*)d_in[10];
    float* out = (float*)d_out;

    const int B = in_sizes[0] / SEQ;     // 2048
    seq2seq_kernel<<<B, 128, 0, stream>>>(src, eWih, eWhh, eBih, eBhh,
                                          dWih, dWhh, dBih, dBhh, fcW, fcB, out);
}